// Round 6
// baseline (613.875 us; speedup 1.0000x reference)
//
#include <hip/hip_runtime.h>
#include <math.h>

#define HD   64
#define EIN  8
#define SAS  168          // sA/sW1 row stride in u16 (336 B): 20*m mod 32 -> conflict-light
#define W2S  72           // sW2 row stride in u16 (144 B)
#define NORM_INV 0.01f
#define NBLK 768          // 3 blocks/CU x 256 CUs

typedef short bf16x8 __attribute__((ext_vector_type(8)));
typedef float f32x4  __attribute__((ext_vector_type(4)));
typedef float f4v    __attribute__((ext_vector_type(4)));

__device__ __forceinline__ unsigned short f2bf(float f) {
    union { float f; unsigned u; } v; v.f = f;
    unsigned r = v.u + 0x7FFFu + ((v.u >> 16) & 1u);
    return (unsigned short)(r >> 16);
}
__device__ __forceinline__ unsigned pk2(float a, float b) {
    return (unsigned)f2bf(a) | ((unsigned)f2bf(b) << 16);
}
__device__ __forceinline__ float silu_f(float x) {
    return x * __builtin_amdgcn_rcpf(1.0f + __expf(-x));
}

__global__ void prep_out_kernel(const float* __restrict__ coord,
                                float* __restrict__ out, int n3) {
    int i = blockIdx.x * blockDim.x + threadIdx.x;
    if (i < n3) out[i] = coord[i];
}

// Barrier-free wave-owned pipeline with register prefetch.
// Each wave owns a CONTIGUOUS span of 16-edge groups. Per group:
//   ds_write staged bf16 regs -> MFMA L1 -> X1 (reg->LDS, packed) -> MFMA L2
//   -> register epilogue (shfl-reduced dot, prefetched coord) -> atomics.
// Next group's gathers are issued before L1 and packed between L1 and L2.
// eidx/eattr are non-temporal (one-shot streams) so they don't evict h from L2.
__global__ __launch_bounds__(256, 3) void egnn_mfma_kernel(
    const float* __restrict__ h,
    const float* __restrict__ coord,
    const int*   __restrict__ eidx,
    const float* __restrict__ eattr,
    const float* __restrict__ W1f,    // [136][64] fp32
    const float* __restrict__ W2f,    // [64][64] fp32
    const float* __restrict__ b1,
    const float* __restrict__ b2,
    const float* __restrict__ W3,
    float* __restrict__ out,
    int E_)
{
    __shared__ unsigned short sW1[64 * SAS];
    __shared__ unsigned short sW2[64 * W2S];
    __shared__ float sB1[64], sB2[64], sW3[64];
    __shared__ unsigned short sA[64 * SAS];    // 4 waves x 16 edge rows

    const int t = threadIdx.x;

    // ---- weights -> LDS (once per block) ----
    for (int i = t; i < 136 * 64; i += 256) {
        int k = i >> 6, n = i & 63;
        sW1[n * SAS + k] = f2bf(W1f[i]);
    }
    for (int i = t; i < 24 * 64; i += 256) {   // zero-pad W1 k=136..159
        int n = i / 24, k = 136 + (i - n * 24);
        sW1[n * SAS + k] = 0;
    }
    for (int i = t; i < 64 * 64; i += 256) {
        int k = i >> 6, n = i & 63;
        sW2[n * W2S + k] = f2bf(W2f[i]);
    }
    if (t < 64) sB1[t] = b1[t];
    else if (t < 128) sB2[t - 64] = b2[t - 64];
    else if (t < 192) sW3[t - 128] = W3[t - 128];
    __syncthreads();                            // the ONLY barrier

    const int w = t >> 6, lane = t & 63;
    const int m = lane & 15, q = lane >> 4;
    const int sm = lane >> 2, sp = lane & 3;    // staging: 4 lanes per edge

    unsigned short* stageRow = sA + (16 * w + sm) * SAS;
    unsigned short* fragRow  = sA + (16 * w + m) * SAS;

    // zero-pad k=136..159 of this wave's rows ONCE (X1 aliases k=0..63 only)
    if (sp < 3) {
        uint4 z; z.x = z.y = z.z = z.w = 0;
        *((uint4*)(stageRow + 136 + sp * 8)) = z;
    }

    // lane-resident bias/W3 fragments
    float4 b1v[4], b2v[4], w3v[4];
#pragma unroll
    for (int nt = 0; nt < 4; ++nt) {
        b1v[nt] = *(const float4*)(&sB1[16 * nt + 4 * q]);
        b2v[nt] = *(const float4*)(&sB2[16 * nt + 4 * q]);
        w3v[nt] = *(const float4*)(&sW3[16 * nt + 4 * q]);
    }

    // ---- contiguous span for this wave ----
    const int ngroups = (E_ + 15) >> 4;
    const int nwaves  = NBLK * 4;
    const int gpw = (ngroups + nwaves - 1) / nwaves;
    const int wid = blockIdx.x * 4 + w;
    const int g0 = wid * gpw;
    const int g1 = (g0 + gpw < ngroups) ? (g0 + gpw) : ngroups;
    if (g0 >= ngroups) return;

    // prefetch buffers
    f4v  hN[8];            // 32 fp32: this lane's half-row of h
    f4v  epN;              // sp odd: one float4 of edge_attr
    int  nodeN;
    uint4 pk[4];           // packed bf16 staged data
    unsigned pkE0, pkE1;   // packed edge_attr (sp odd)
    int  node;

    auto load_group = [&](int g) {
        int e = g * 16 + sm;
        int ec = (e < E_) ? e : (E_ - 1);
        nodeN = (sp < 2) ? __builtin_nontemporal_load(&eidx[ec])
                         : __builtin_nontemporal_load(&eidx[(size_t)E_ + ec]);
        const f4v* src = (const f4v*)(h + (size_t)nodeN * HD) + (sp & 1) * 8;
#pragma unroll
        for (int i = 0; i < 8; ++i) hN[i] = src[i];
        if (sp & 1) {
            const f4v* eap = (const f4v*)(eattr + (size_t)ec * EIN) + (sp >> 1);
            epN = __builtin_nontemporal_load(eap);
        }
    };
    auto pack_group = [&]() {
#pragma unroll
        for (int i = 0; i < 4; ++i) {
            f4v a = hN[2 * i], b = hN[2 * i + 1];
            pk[i].x = pk2(a.x, a.y); pk[i].y = pk2(a.z, a.w);
            pk[i].z = pk2(b.x, b.y); pk[i].w = pk2(b.z, b.w);
        }
        pkE0 = pk2(epN.x, epN.y); pkE1 = pk2(epN.z, epN.w);
        node = nodeN;
    };

    load_group(g0);
    pack_group();

    for (int g = g0; g < g1; ++g) {
        // ---------- stage current group's packed regs into sA ----------
        {
            uint4* dst = (uint4*)stageRow + sp * 4;   // k in [32*sp, 32*sp+32)
#pragma unroll
            for (int i = 0; i < 4; ++i) dst[i] = pk[i];
            if (sp & 1) {                             // edge_attr k=128..135
                uint2 v; v.x = pkE0; v.y = pkE1;
                *((uint2*)(stageRow + 128 + (sp >> 1) * 4)) = v;
            }
        }

        // epilogue indices via shfl (no eidx re-read); issue coord loads NOW
        int rI = __shfl(node, 4 * m);
        int cI = __shfl(node, 4 * m + 2);
        float cr = 0.f, cc = 0.f;
        if (q < 3) { cr = coord[rI * 3 + q]; cc = coord[cI * 3 + q]; }

        // issue next group's gathers (results consumed at pack point below)
        if (g + 1 < g1) load_group(g + 1);

        // ---------- layer 1: D1[n2][e] = sum_k W1[n2][k] * inp[e][k] ----------
        f32x4 acc1[4] = {};
#pragma unroll
        for (int s = 0; s < 5; ++s) {
            bf16x8 bfrag = *(const bf16x8*)(fragRow + s * 32 + q * 8);
#pragma unroll
            for (int nt = 0; nt < 4; ++nt) {
                bf16x8 afrag = *(const bf16x8*)(sW1 + (16 * nt + m) * SAS + s * 32 + q * 8);
                acc1[nt] = __builtin_amdgcn_mfma_f32_16x16x32_bf16(afrag, bfrag, acc1[nt], 0, 0, 0);
            }
        }

        // silu -> X1 at row offset 0 (k=0..63), packed b64 per lane
#pragma unroll
        for (int nt = 0; nt < 4; ++nt) {
            ushort4 o;
            o.x = f2bf(silu_f(acc1[nt][0] + b1v[nt].x));
            o.y = f2bf(silu_f(acc1[nt][1] + b1v[nt].y));
            o.z = f2bf(silu_f(acc1[nt][2] + b1v[nt].z));
            o.w = f2bf(silu_f(acc1[nt][3] + b1v[nt].w));
            *((ushort4*)(fragRow + 16 * nt + 4 * q)) = o;
        }

        // pack next group's gathers (vmcnt waits land here, mid-pipeline)
        if (g + 1 < g1) pack_group();

        // ---------- layer 2: D2[n2][e] = sum_k W2[n2][k] * X1[e][k] ----------
        f32x4 acc2[4] = {};
#pragma unroll
        for (int s = 0; s < 2; ++s) {
            bf16x8 bfrag = *(const bf16x8*)(fragRow + s * 32 + q * 8);
#pragma unroll
            for (int nt = 0; nt < 4; ++nt) {
                bf16x8 afrag = *(const bf16x8*)(sW2 + (16 * nt + m) * W2S + s * 32 + q * 8);
                acc2[nt] = __builtin_amdgcn_mfma_f32_16x16x32_bf16(afrag, bfrag, acc2[nt], 0, 0, 0);
            }
        }

        // ---------- epilogue: scal = silu(X2) . W3, all in registers ----------
        float p = 0.f;
#pragma unroll
        for (int nt = 0; nt < 4; ++nt) {
            p = fmaf(silu_f(acc2[nt][0] + b2v[nt].x), w3v[nt].x, p);
            p = fmaf(silu_f(acc2[nt][1] + b2v[nt].y), w3v[nt].y, p);
            p = fmaf(silu_f(acc2[nt][2] + b2v[nt].z), w3v[nt].z, p);
            p = fmaf(silu_f(acc2[nt][3] + b2v[nt].w), w3v[nt].w, p);
        }
        p += __shfl_xor(p, 16);
        p += __shfl_xor(p, 32);

        // distributed coord-diff: lane (q,m) owns component q of edge m
        float cd = cr - cc;                       // q==3 lanes: 0
        float r2 = cd * cd;
        r2 += __shfl_xor(r2, 16);
        r2 += __shfl_xor(r2, 32);                 // radial, all lanes
        int e2 = g * 16 + m;
        if (e2 < E_ && q < 3) {
            float inv = __builtin_amdgcn_rcpf(sqrtf(r2 + 1e-8f) + 1.0f);
            atomicAdd(&out[rI * 3 + q], cd * (p * NORM_INV * inv));
        }
    }
}

extern "C" void kernel_launch(void* const* d_in, const int* in_sizes, int n_in,
                              void* d_out, int out_size, void* d_ws, size_t ws_size,
                              hipStream_t stream) {
    const float* h         = (const float*)d_in[0];
    const float* coord     = (const float*)d_in[1];
    const int*   eidx      = (const int*)  d_in[2];
    const float* edge_attr = (const float*)d_in[3];
    const float* W1        = (const float*)d_in[4];
    const float* b1        = (const float*)d_in[5];
    const float* W2        = (const float*)d_in[6];
    const float* b2        = (const float*)d_in[7];
    const float* W3        = (const float*)d_in[8];
    float* out = (float*)d_out;

    int E_ = in_sizes[2] / 2;    // edge_index is [2, E]
    int n3 = out_size;           // N*3

    hipLaunchKernelGGL(prep_out_kernel, dim3((n3 + 255) / 256), dim3(256), 0, stream,
                       coord, out, n3);
    hipLaunchKernelGGL(egnn_mfma_kernel, dim3(NBLK), dim3(256), 0, stream,
                       h, coord, eidx, edge_attr, W1, W2, b1, b2, W3, out, E_);
}